// Round 1
// baseline (112.862 us; speedup 1.0000x reference)
//
#include <hip/hip_runtime.h>

// GraphProposalNetwork on MI355X.
// Structure: feat = x@Wp+bp is LINEAR into W1, and pair=[vi,vj], so
//   h1[b,i,j,:] = lrelu( g_a[b,i,:] + g_b[b,j,:] )
// with g_a = x @ (Wp@W1[0:16]) + (bp@W1[0:16] + b1),  g_b = x @ (Wp@W1[16:32]) + bp@W1[16:32].
// Per-node 3->64 projection replaces the per-edge 32x32 layer (160x less L1 work).

constexpr int N_NODES = 10;
constexpr int G = 8;                 // graphs per block
constexpr int NODES = G * N_NODES;   // 80
constexpr int GSTRIDE = 68;          // padded row stride (floats): 16B aligned, bank-rotate 4
constexpr int EDGES = G * N_NODES * N_NODES;  // 800
constexpr float NEG = 0.2f;

__global__ __launch_bounds__(256, 4) void gpn_kernel(
    const float* __restrict__ pos,  // (B,10,2)
    const float* __restrict__ ori,  // (B,10,1)
    const float* __restrict__ Wp,   // (3,16)
    const float* __restrict__ bp,   // (16)
    const float* __restrict__ W1,   // (32,32)
    const float* __restrict__ b1,   // (32)
    const float* __restrict__ W2,   // (32,8)
    const float* __restrict__ b2,   // (8)
    const float* __restrict__ W3,   // (8,2)
    const float* __restrict__ b3,   // (2)
    float* __restrict__ out,        // big_edge (B*100*2) ++ adjacency (B*100) as float
    int B)
{
    __shared__ float sW1[32 * 32];
    __shared__ float sWp[3 * 16];
    __shared__ float sbp[16];
    __shared__ float sb1[32];
    __shared__ float sM[3 * 64];     // fused Wp@[W1a|W1b]
    __shared__ float sc[64];         // fused bias: bp@[W1a|W1b] (+ b1 folded into first 32)
    __shared__ float sx[NODES * 3];  // (px,py,o) per node
    __shared__ float sg[NODES * GSTRIDE];

    const int t = threadIdx.x;
    const int bBase = blockIdx.x * G;

    // ---- stage weights + node inputs into LDS ----
    for (int idx = t; idx < 32 * 32; idx += 256) sW1[idx] = W1[idx];
    if (t < 48)       sWp[t]      = Wp[t];
    else if (t < 64)  sbp[t - 48] = bp[t - 48];
    else if (t < 96)  sb1[t - 64] = b1[t - 64];

    if (t < G * N_NODES * 2) {  // 160 position floats
        int bl = t / 20, r = t % 20;
        int n = r >> 1, d = r & 1;
        sx[(bl * N_NODES + n) * 3 + d] = pos[bBase * (N_NODES * 2) + t];
    } else if (t < G * N_NODES * 2 + G * N_NODES) {  // 80 orientation floats
        int u = t - G * N_NODES * 2;
        sx[u * 3 + 2] = ori[bBase * N_NODES + u];
    }
    __syncthreads();

    // ---- fuse M = Wp @ [W1a | W1b]  (3x64)  and c = bp @ [W1a | W1b] (+b1) ----
    if (t < 192) {
        int d = t >> 6, k = t & 63;
        int kk = (k < 32) ? k : (k - 32);
        int fo = (k < 32) ? 0 : 16;
        float acc = 0.f;
#pragma unroll
        for (int f = 0; f < 16; ++f)
            acc = fmaf(sWp[d * 16 + f], sW1[(fo + f) * 32 + kk], acc);
        sM[d * 64 + k] = acc;
    } else {
        int k = t - 192;
        int kk = (k < 32) ? k : (k - 32);
        int fo = (k < 32) ? 0 : 16;
        float acc = 0.f;
#pragma unroll
        for (int f = 0; f < 16; ++f)
            acc = fmaf(sbp[f], sW1[(fo + f) * 32 + kk], acc);
        if (k < 32) acc += sb1[k];  // fold b1 into the g_a half
        sc[k] = acc;
    }
    __syncthreads();

    // ---- per-node projection: g[node][k] = x . M[:,k] + c[k] ----
    {
        int k = t & 63;
        int ng = t >> 6;  // 0..3; whole wave shares one node -> broadcast sx reads
        float m0 = sM[k], m1 = sM[64 + k], m2 = sM[128 + k];
        float ck = sc[k];
        for (int n = ng; n < NODES; n += 4) {
            float g = fmaf(sx[n * 3 + 0], m0,
                      fmaf(sx[n * 3 + 1], m1,
                      fmaf(sx[n * 3 + 2], m2, ck)));
            sg[n * GSTRIDE + k] = g;
        }
    }
    __syncthreads();

    // ---- per-edge MLP: h1 = lrelu(gi+gj); h2 = lrelu(h1@W2+b2); e = h2@W3+b3 ----
    const float4* sg4 = (const float4*)sg;  // 17 float4 per row
    const size_t adjOff = (size_t)B * (N_NODES * N_NODES) * 2;

    for (int e = t; e < EDGES; e += 256) {
        int bl = e / 100, rem = e % 100;
        int i = rem / 10, c = rem % 10;
        int j = (c == 0) ? i : (((c - 1) < i) ? (c - 1) : c);
        int ni = bl * N_NODES + i;
        int nj = bl * N_NODES + j;

        float h1[32];
#pragma unroll
        for (int q = 0; q < 8; ++q) {
            float4 a = sg4[ni * (GSTRIDE / 4) + q];       // g_a half (k=0..31)
            float4 b = sg4[nj * (GSTRIDE / 4) + 8 + q];   // g_b half (k=32..63)
            float s0 = a.x + b.x, s1 = a.y + b.y, s2 = a.z + b.z, s3 = a.w + b.w;
            h1[4 * q + 0] = fmaxf(s0, NEG * s0);
            h1[4 * q + 1] = fmaxf(s1, NEG * s1);
            h1[4 * q + 2] = fmaxf(s2, NEG * s2);
            h1[4 * q + 3] = fmaxf(s3, NEG * s3);
        }

        float acc[8] = {0.f, 0.f, 0.f, 0.f, 0.f, 0.f, 0.f, 0.f};
#pragma unroll
        for (int k = 0; k < 32; ++k) {
            float h = h1[k];
#pragma unroll
            for (int m = 0; m < 8; ++m)
                acc[m] = fmaf(h, W2[k * 8 + m], acc[m]);  // W2 uniform -> s_load
        }

        float e0 = 0.f, e1 = 0.f;
#pragma unroll
        for (int m = 0; m < 8; ++m) {
            float h2 = acc[m] + b2[m];
            h2 = fmaxf(h2, NEG * h2);
            e0 = fmaf(h2, W3[m * 2 + 0], e0);
            e1 = fmaf(h2, W3[m * 2 + 1], e1);
        }
        e0 += b3[0];
        e1 += b3[1];

        int E = bBase * (N_NODES * N_NODES) + e;
        ((float2*)out)[E] = make_float2(e0, e1);
        out[adjOff + E] = (e1 > e0) ? 1.0f : 0.0f;  // argmax over 2 (ties -> 0, like np)
    }
}

extern "C" void kernel_launch(void* const* d_in, const int* in_sizes, int n_in,
                              void* d_out, int out_size, void* d_ws, size_t ws_size,
                              hipStream_t stream) {
    const float* pos = (const float*)d_in[0];
    const float* ori = (const float*)d_in[1];
    const float* Wp  = (const float*)d_in[2];
    const float* bp  = (const float*)d_in[3];
    const float* W1  = (const float*)d_in[4];
    const float* b1  = (const float*)d_in[5];
    const float* W2  = (const float*)d_in[6];
    const float* b2  = (const float*)d_in[7];
    const float* W3  = (const float*)d_in[8];
    const float* b3  = (const float*)d_in[9];
    float* out = (float*)d_out;

    const int B = in_sizes[0] / (N_NODES * 2);  // 16384
    const int nBlocks = B / G;                  // 2048

    gpn_kernel<<<nBlocks, 256, 0, stream>>>(pos, ori, Wp, bp, W1, b1, W2, b2,
                                            W3, b3, out, B);
}

// Round 2
// 108.971 us; speedup vs baseline: 1.0357x; 1.0357x over previous
//
#include <hip/hip_runtime.h>

// GraphProposalNetwork on MI355X — round 2.
// Algebra: feat=x@Wp+bp is linear into W1 and pair=[vi,vj], so
//   h1[b,i,j,:] = lrelu(g_a[b,i,:] + g_b[b,j,:])  with per-node g = x@(Wp@W1half)+bias.
// Round-2 changes: packed-fp32 (v_pk_fma_f32) edge MLP over the m-dimension;
// W1 staging aliased into sg storage -> LDS 28.7->23.8 KB -> 6 blocks/CU.

typedef float v2f __attribute__((ext_vector_type(2)));
typedef float v4f __attribute__((ext_vector_type(4)));

constexpr int N_NODES = 10;
constexpr int G = 8;                  // graphs per block
constexpr int NODES = G * N_NODES;    // 80
constexpr int GSTRIDE = 68;           // padded row stride (floats): float4-aligned, bank-rotate 4
constexpr int EDGES = G * 100;        // 800
constexpr float NEG = 0.2f;

__global__ __launch_bounds__(256, 6) void gpn_kernel(
    const float* __restrict__ pos,  // (B,10,2)
    const float* __restrict__ ori,  // (B,10,1)
    const float* __restrict__ Wp,   // (3,16)
    const float* __restrict__ bp,   // (16)
    const float* __restrict__ W1,   // (32,32)
    const float* __restrict__ b1,   // (32)
    const float* __restrict__ W2,   // (32,8)
    const float* __restrict__ b2,   // (8)
    const float* __restrict__ W3,   // (8,2)
    const float* __restrict__ b3,   // (2)
    float* __restrict__ out,        // big_edge (B*100*2) ++ adjacency (B*100) as float
    int B)
{
    // W1/Wp/bp/b1 staging is dead after the fuse phase; alias it into sg storage.
    __shared__ union SU {
        struct { float W1[1024]; float Wp[48]; float bp[16]; float b1[32]; } w;
        float g[NODES * GSTRIDE];   // 5440 floats = 21760 B (>= 1120 floats of w)
    } sU;
    __shared__ float sM[3 * 64];    // fused Wp@[W1a|W1b]
    __shared__ float sc[64];        // fused bias (b1 folded into first 32)
    __shared__ float sx[NODES * 3]; // (px,py,o) per node

    const int t = threadIdx.x;
    const int bBase = blockIdx.x * G;

    // ---- phase 1: stage weights + node inputs ----
    for (int idx = t; idx < 1024; idx += 256) sU.w.W1[idx] = W1[idx];
    if (t < 48)       sU.w.Wp[t]      = Wp[t];
    else if (t < 64)  sU.w.bp[t - 48] = bp[t - 48];
    else if (t < 96)  sU.w.b1[t - 64] = b1[t - 64];

    if (t < NODES * 2) {            // 160 position floats
        int u = t;
        int n = u >> 1, d = u & 1;
        sx[n * 3 + d] = pos[bBase * (N_NODES * 2) + u];
    } else if (t < NODES * 2 + NODES) {  // 80 orientation floats
        int u = t - NODES * 2;
        sx[u * 3 + 2] = ori[bBase * N_NODES + u];
    }
    __syncthreads();

    // ---- phase 2: fuse M = Wp@[W1a|W1b] (3x64), c = bp@[W1a|W1b] (+b1) ----
    if (t < 192) {
        int d = t >> 6, k = t & 63;
        int kk = k & 31;
        int fo = (k < 32) ? 0 : 16;
        float acc = 0.f;
#pragma unroll
        for (int f = 0; f < 16; ++f)
            acc = fmaf(sU.w.Wp[d * 16 + f], sU.w.W1[(fo + f) * 32 + kk], acc);
        sM[d * 64 + k] = acc;
    } else if (t < 256) {
        int k = t - 192;
        int kk = k & 31;
        int fo = (k < 32) ? 0 : 16;
        float acc = 0.f;
#pragma unroll
        for (int f = 0; f < 16; ++f)
            acc = fmaf(sU.w.bp[f], sU.w.W1[(fo + f) * 32 + kk], acc);
        if (k < 32) acc += sU.w.b1[k];
        sc[k] = acc;
    }
    __syncthreads();

    // ---- phase 3: per-node projection g[n][k] = x.M[:,k] + c[k] ----
    {
        int k = t & 63;
        int ng = t >> 6;
        float m0 = sM[k], m1 = sM[64 + k], m2 = sM[128 + k];
        float ck = sc[k];
        for (int n = ng; n < NODES; n += 4) {
            float g = fmaf(sx[n * 3 + 0], m0,
                      fmaf(sx[n * 3 + 1], m1,
                      fmaf(sx[n * 3 + 2], m2, ck)));
            sU.g[n * GSTRIDE + k] = g;
        }
    }
    __syncthreads();

    // ---- phase 4: per-edge MLP, packed-fp32 over the m dimension ----
    const v4f* g4 = (const v4f*)sU.g;          // GSTRIDE/4 = 17 float4 per row
    const v2f* w2p = (const v2f*)W2;           // row k: w2p[4k + m2], uniform -> s_load
    const v2f* w3p = (const v2f*)W3;           // row m: (W3[m][0], W3[m][1])
    const v2f* b2p = (const v2f*)b2;
    const v2f* b3p = (const v2f*)b3;
    const size_t adjOff = (size_t)B * 200;

    for (int e = t; e < EDGES; e += 256) {
        int bl = e / 100, rem = e - bl * 100;
        int i = rem / 10, c = rem - i * 10;
        int j = (c == 0) ? i : (((c - 1) < i) ? (c - 1) : c);
        const int ra = (bl * N_NODES + i) * (GSTRIDE / 4);
        const int rb = (bl * N_NODES + j) * (GSTRIDE / 4) + 8;

        // h1 = lrelu(ga + gb), kept as 16 packed pairs (k-major)
        v2f h[16];
#pragma unroll
        for (int q = 0; q < 8; ++q) {
            v4f a = g4[ra + q];
            v4f b = g4[rb + q];
            v4f s = a + b;
            v4f hh = __builtin_elementwise_max(s, s * NEG);
            h[2 * q + 0] = hh.xy;
            h[2 * q + 1] = hh.zw;
        }

        // layer 2: acc(m-pairs) += h_k * W2[k][m-pair]   (v_pk_fma_f32)
        v2f a0 = b2p[0], a1 = b2p[1], a2 = b2p[2], a3 = b2p[3];
#pragma unroll
        for (int k2 = 0; k2 < 16; ++k2) {
            v2f hp = h[k2];
            v2f hx = {hp.x, hp.x};
            v2f hy = {hp.y, hp.y};
            const int k0 = 2 * k2, k1 = 2 * k2 + 1;
            a0 = __builtin_elementwise_fma(hx, w2p[4 * k0 + 0], a0);
            a1 = __builtin_elementwise_fma(hx, w2p[4 * k0 + 1], a1);
            a2 = __builtin_elementwise_fma(hx, w2p[4 * k0 + 2], a2);
            a3 = __builtin_elementwise_fma(hx, w2p[4 * k0 + 3], a3);
            a0 = __builtin_elementwise_fma(hy, w2p[4 * k1 + 0], a0);
            a1 = __builtin_elementwise_fma(hy, w2p[4 * k1 + 1], a1);
            a2 = __builtin_elementwise_fma(hy, w2p[4 * k1 + 2], a2);
            a3 = __builtin_elementwise_fma(hy, w2p[4 * k1 + 3], a3);
        }

        // layer 3: lrelu then 8->2
        v2f h20 = __builtin_elementwise_max(a0, a0 * NEG);
        v2f h21 = __builtin_elementwise_max(a1, a1 * NEG);
        v2f h22 = __builtin_elementwise_max(a2, a2 * NEG);
        v2f h23 = __builtin_elementwise_max(a3, a3 * NEG);

        v2f ev = b3p[0];
        v2f s0 = {h20.x, h20.x}, s1 = {h20.y, h20.y};
        ev = __builtin_elementwise_fma(s0, w3p[0], ev);
        ev = __builtin_elementwise_fma(s1, w3p[1], ev);
        v2f s2 = {h21.x, h21.x}, s3 = {h21.y, h21.y};
        ev = __builtin_elementwise_fma(s2, w3p[2], ev);
        ev = __builtin_elementwise_fma(s3, w3p[3], ev);
        v2f s4 = {h22.x, h22.x}, s5 = {h22.y, h22.y};
        ev = __builtin_elementwise_fma(s4, w3p[4], ev);
        ev = __builtin_elementwise_fma(s5, w3p[5], ev);
        v2f s6 = {h23.x, h23.x}, s7 = {h23.y, h23.y};
        ev = __builtin_elementwise_fma(s6, w3p[6], ev);
        ev = __builtin_elementwise_fma(s7, w3p[7], ev);

        const int E = bBase * 100 + e;
        ((v2f*)out)[E] = ev;                        // global_store_dwordx2, coalesced
        out[adjOff + E] = (ev.y > ev.x) ? 1.0f : 0.0f;
    }
}

extern "C" void kernel_launch(void* const* d_in, const int* in_sizes, int n_in,
                              void* d_out, int out_size, void* d_ws, size_t ws_size,
                              hipStream_t stream) {
    const float* pos = (const float*)d_in[0];
    const float* ori = (const float*)d_in[1];
    const float* Wp  = (const float*)d_in[2];
    const float* bp  = (const float*)d_in[3];
    const float* W1  = (const float*)d_in[4];
    const float* b1  = (const float*)d_in[5];
    const float* W2  = (const float*)d_in[6];
    const float* b2  = (const float*)d_in[7];
    const float* W3  = (const float*)d_in[8];
    const float* b3  = (const float*)d_in[9];
    float* out = (float*)d_out;

    const int B = in_sizes[0] / (N_NODES * 2);  // 16384
    const int nBlocks = B / G;                  // 2048

    gpn_kernel<<<nBlocks, 256, 0, stream>>>(pos, ori, Wp, bp, W1, b1, W2, b2,
                                            W3, b3, out, B);
}

// Round 3
// 103.956 us; speedup vs baseline: 1.0857x; 1.0482x over previous
//
#include <hip/hip_runtime.h>

// GraphProposalNetwork on MI355X — round 3.
// Algebra: feat=x@Wp+bp is linear into W1 and pair=[vi,vj], so
//   h1[b,i,j,:] = lrelu(g_a[b,i,:] + g_b[b,j,:]) with per-node g = x@(Wp@W1half)+bias.
// Round-3 restructure: lane <-> (graph,i) node; g_a half lives in registers and is
// reused across the 10 j-edges (LDS reads halve); no per-edge div/mod; no W1 LDS
// staging (read coalesced from L2 in the fuse phase); batched dwordx4 stores.

typedef float v2f __attribute__((ext_vector_type(2)));
typedef float v4f __attribute__((ext_vector_type(4)));

constexpr int G = 25;            // graphs per block (250 of 256 lanes active)
constexpr int GB_STRIDE = 36;    // floats per gb row: 32 + 4 pad (16B aligned)
constexpr float NEG = 0.2f;

__global__ __launch_bounds__(256, 4) void gpn_kernel(
    const float* __restrict__ pos,  // (B,10,2)
    const float* __restrict__ ori,  // (B,10,1)
    const float* __restrict__ Wp,   // (3,16)
    const float* __restrict__ bp,   // (16)
    const float* __restrict__ W1,   // (32,32)
    const float* __restrict__ b1,   // (32)
    const float* __restrict__ W2,   // (32,8)
    const float* __restrict__ b2,   // (8)
    const float* __restrict__ W3,   // (8,2)
    const float* __restrict__ b3,   // (2)
    float* __restrict__ out,        // big_edge (B*100*2) ++ adjacency (B*100)
    int B)
{
    __shared__ float sM[3 * 64];                 // fused Wp@[W1a|W1b]
    __shared__ float sc[64];                     // fused bias (b1 folded into first 32)
    __shared__ float sgb[G * 10 * GB_STRIDE];    // per-node g_b halves (36 KB)

    const int t = threadIdx.x;
    const int bBase = blockIdx.x * G;
    const int remG = B - bBase;
    const int nNodes = ((remG < G) ? remG : G) * 10;

    // ---- Phase A: fuse M = Wp@[W1a|W1b] (3x64), c = bp@[W1a|W1b] (+b1) ----
    // W1 read coalesced straight from global (L2-hot after first blocks).
    {
        if (t < 192) {
            const int d = t >> 6, k = t & 63;
            const int kk = k & 31;
            const int fo = (k < 32) ? 0 : 16;
            float acc = 0.f;
#pragma unroll
            for (int f = 0; f < 16; ++f)
                acc = fmaf(Wp[d * 16 + f], W1[(fo + f) * 32 + kk], acc);
            sM[d * 64 + k] = acc;
        } else {
            const int k = t - 192;
            const int kk = k & 31;
            const int fo = (k < 32) ? 0 : 16;
            float acc = 0.f;
#pragma unroll
            for (int f = 0; f < 16; ++f)
                acc = fmaf(bp[f], W1[(fo + f) * 32 + kk], acc);
            if (k < 32) acc += b1[k];
            sc[k] = acc;
        }
    }
    __syncthreads();

    // ---- Phase B: per-node projection. Lane owns node (g,i); computes all 64
    // g values; keeps a-half (k<32) in registers, writes b-half to LDS. ----
    v4f ga[8];
    const int g = t / 10;
    const int i = t - g * 10;
    if (t < nNodes) {
        const int node = bBase * 10 + t;
        const v2f p = ((const v2f*)pos)[node];
        const float o = ori[node];
        const v4f* m4 = (const v4f*)sM;   // [48]
        const v4f* c4 = (const v4f*)sc;   // [16]
        v4f* dst = (v4f*)&sgb[t * GB_STRIDE];
#pragma unroll
        for (int q = 0; q < 16; ++q) {
            v4f gg = c4[q];
            gg += p.x * m4[q];
            gg += p.y * m4[16 + q];
            gg += o   * m4[32 + q];
            if (q < 8) ga[q] = gg;
            else       dst[q - 8] = gg;
        }
    }
    __syncthreads();

    // ---- Phase C: 10 edges per lane; ga reused from registers, gb from LDS ----
    if (t < nNodes) {
        const v2f* w2p = (const v2f*)W2;  // row k: pairs [4k..4k+3], uniform -> s_load
        const v2f* w3p = (const v2f*)W3;
        const v2f bb2_0 = ((const v2f*)b2)[0];
        const v2f bb2_1 = ((const v2f*)b2)[1];
        const v2f bb2_2 = ((const v2f*)b2)[2];
        const v2f bb2_3 = ((const v2f*)b2)[3];
        const v2f bb3   = ((const v2f*)b3)[0];

        float evb[20];
        float adj[10];

#pragma unroll
        for (int c = 0; c < 10; ++c) {
            const int j = (c == 0) ? i : (((c - 1) < i) ? (c - 1) : c);
            const v4f* src = (const v4f*)&sgb[(g * 10 + j) * GB_STRIDE];

            v2f a0 = bb2_0, a1 = bb2_1, a2 = bb2_2, a3 = bb2_3;
#pragma unroll
            for (int q = 0; q < 8; ++q) {
                const v4f s = ga[q] + src[q];
                const v4f h = __builtin_elementwise_max(s, s * NEG);
                const int k0 = 4 * q;
                a0 += h.x * w2p[4 * (k0 + 0) + 0];
                a1 += h.x * w2p[4 * (k0 + 0) + 1];
                a2 += h.x * w2p[4 * (k0 + 0) + 2];
                a3 += h.x * w2p[4 * (k0 + 0) + 3];
                a0 += h.y * w2p[4 * (k0 + 1) + 0];
                a1 += h.y * w2p[4 * (k0 + 1) + 1];
                a2 += h.y * w2p[4 * (k0 + 1) + 2];
                a3 += h.y * w2p[4 * (k0 + 1) + 3];
                a0 += h.z * w2p[4 * (k0 + 2) + 0];
                a1 += h.z * w2p[4 * (k0 + 2) + 1];
                a2 += h.z * w2p[4 * (k0 + 2) + 2];
                a3 += h.z * w2p[4 * (k0 + 2) + 3];
                a0 += h.w * w2p[4 * (k0 + 3) + 0];
                a1 += h.w * w2p[4 * (k0 + 3) + 1];
                a2 += h.w * w2p[4 * (k0 + 3) + 2];
                a3 += h.w * w2p[4 * (k0 + 3) + 3];
            }

            const v2f h20 = __builtin_elementwise_max(a0, a0 * NEG);
            const v2f h21 = __builtin_elementwise_max(a1, a1 * NEG);
            const v2f h22 = __builtin_elementwise_max(a2, a2 * NEG);
            const v2f h23 = __builtin_elementwise_max(a3, a3 * NEG);

            v2f ev = bb3;
            ev += h20.x * w3p[0];
            ev += h20.y * w3p[1];
            ev += h21.x * w3p[2];
            ev += h21.y * w3p[3];
            ev += h22.x * w3p[4];
            ev += h22.y * w3p[5];
            ev += h23.x * w3p[6];
            ev += h23.y * w3p[7];

            evb[2 * c]     = ev.x;
            evb[2 * c + 1] = ev.y;
            adj[c] = (ev.y > ev.x) ? 1.0f : 0.0f;
        }

        // ---- batched stores: 5x dwordx4 big_edge + 5x dwordx2 adjacency ----
        const int eBase = (bBase * 10 + t) * 10;        // first edge of this row
        v4f* bo = (v4f*)(out + (size_t)eBase * 2);      // 80B-aligned
#pragma unroll
        for (int q = 0; q < 5; ++q) {
            v4f vv = {evb[4 * q], evb[4 * q + 1], evb[4 * q + 2], evb[4 * q + 3]};
            bo[q] = vv;
        }
        v2f* ao = (v2f*)(out + (size_t)B * 200 + eBase); // 40B base -> 8B aligned
#pragma unroll
        for (int q = 0; q < 5; ++q) {
            v2f vv = {adj[2 * q], adj[2 * q + 1]};
            ao[q] = vv;
        }
    }
}

extern "C" void kernel_launch(void* const* d_in, const int* in_sizes, int n_in,
                              void* d_out, int out_size, void* d_ws, size_t ws_size,
                              hipStream_t stream) {
    const float* pos = (const float*)d_in[0];
    const float* ori = (const float*)d_in[1];
    const float* Wp  = (const float*)d_in[2];
    const float* bp  = (const float*)d_in[3];
    const float* W1  = (const float*)d_in[4];
    const float* b1  = (const float*)d_in[5];
    const float* W2  = (const float*)d_in[6];
    const float* b2  = (const float*)d_in[7];
    const float* W3  = (const float*)d_in[8];
    const float* b3  = (const float*)d_in[9];
    float* out = (float*)d_out;

    const int B = in_sizes[0] / 20;           // 16384
    const int nBlocks = (B + G - 1) / G;      // 656

    gpn_kernel<<<nBlocks, 256, 0, stream>>>(pos, ori, Wp, bp, W1, b1, W2, b2,
                                            W3, b3, out, B);
}

// Round 4
// 103.507 us; speedup vs baseline: 1.0904x; 1.0043x over previous
//
#include <hip/hip_runtime.h>

// GraphProposalNetwork on MI355X — round 4.
// Algebra: feat=x@Wp+bp is linear into W1 and pair=[vi,vj], so
//   h1[b,i,j,:] = lrelu(g_a[b,i,:] + g_b[b,j,:]) with per-node g = x@(Wp@W1half)+bias.
// Round-4: 2 lanes per (graph,i) row (5 edges each, halves serial chain and live
// state); per-edge immediate stores (no evb/adj register arrays -> no spills);
// G=12 graphs/block, LDS 17.3 KB -> 4 blocks/CU, up to 32 waves/CU.

typedef float v2f __attribute__((ext_vector_type(2)));
typedef float v4f __attribute__((ext_vector_type(4)));

constexpr int G = 12;            // graphs per block (240 of 256 lanes active)
constexpr int GB_STRIDE = 36;    // floats per gb row: 32 + 4 pad (16B aligned)
constexpr float NEG = 0.2f;

__global__ __launch_bounds__(256, 4) void gpn_kernel(
    const float* __restrict__ pos,  // (B,10,2)
    const float* __restrict__ ori,  // (B,10,1)
    const float* __restrict__ Wp,   // (3,16)
    const float* __restrict__ bp,   // (16)
    const float* __restrict__ W1,   // (32,32)
    const float* __restrict__ b1,   // (32)
    const float* __restrict__ W2,   // (32,8)
    const float* __restrict__ b2,   // (8)
    const float* __restrict__ W3,   // (8,2)
    const float* __restrict__ b3,   // (2)
    float* __restrict__ out,        // big_edge (B*100*2) ++ adjacency (B*100)
    int B)
{
    __shared__ float sM[3 * 64];              // fused Wp@[W1a|W1b]
    __shared__ float sc[64];                  // fused bias (b1 folded into first 32)
    __shared__ float sgb[G * 10 * GB_STRIDE]; // per-node g_b halves (17.3 KB)

    const int t = threadIdx.x;
    const int bBase = blockIdx.x * G;         // first graph of this block
    const int remG = B - bBase;
    const int nLanes = ((remG < G) ? remG : G) * 10 * 2;

    // ---- Phase A: fuse M = Wp@[W1a|W1b] (3x64), c = bp@[W1a|W1b] (+b1) ----
    // Wp reads are wave-uniform (s_load); W1 reads coalesce (one line per f).
    if (t < 192) {
        const int d = t >> 6, k = t & 63;
        const int kk = k & 31;
        const int fo = (k < 32) ? 0 : 16;
        float acc = 0.f;
#pragma unroll
        for (int f = 0; f < 16; ++f)
            acc = fmaf(Wp[d * 16 + f], W1[(fo + f) * 32 + kk], acc);
        sM[d * 64 + k] = acc;
    } else {
        const int k = t - 192;
        const int kk = k & 31;
        const int fo = (k < 32) ? 0 : 16;
        float acc = 0.f;
#pragma unroll
        for (int f = 0; f < 16; ++f)
            acc = fmaf(bp[f], W1[(fo + f) * 32 + kk], acc);
        if (k < 32) acc += b1[k];
        sc[k] = acc;
    }
    __syncthreads();

    // ---- Phase B: per-node projection. Two lanes share row r = t>>1; both
    // compute the register a-half (q=0..7); each writes 4 of the 8 b-half
    // float4s to LDS. ----
    v4f ga[8];
    const int r = t >> 1;          // row = (graph,i) within block
    const int half = t & 1;        // which 5-edge half of the row
    const int g = r / 10;
    const int i = r - g * 10;
    if (t < nLanes) {
        const int node = bBase * 10 + r;
        const v2f p = ((const v2f*)pos)[node];
        const float o = ori[node];
        const v4f* m4 = (const v4f*)sM;   // [48]
        const v4f* c4 = (const v4f*)sc;   // [16]
        v4f* dst = (v4f*)&sgb[r * GB_STRIDE];
#pragma unroll
        for (int q = 0; q < 8; ++q) {
            v4f gg = c4[q];
            gg += p.x * m4[q];
            gg += p.y * m4[16 + q];
            gg += o   * m4[32 + q];
            ga[q] = gg;
        }
#pragma unroll
        for (int qq = 0; qq < 4; ++qq) {
            const int q = 8 + half * 4 + qq;
            v4f gg = c4[q];
            gg += p.x * m4[q];
            gg += p.y * m4[16 + q];
            gg += o   * m4[32 + q];
            dst[q - 8] = gg;
        }
    }
    __syncthreads();

    // ---- Phase C: 5 edges per lane; ga from registers, gb from LDS;
    // results stored immediately (no register arrays). ----
    if (t < nLanes) {
        const v2f* w2p = (const v2f*)W2;  // row k: pairs [4k..4k+3], uniform -> s_load
        const v2f* w3p = (const v2f*)W3;
        const v2f bb2_0 = ((const v2f*)b2)[0];
        const v2f bb2_1 = ((const v2f*)b2)[1];
        const v2f bb2_2 = ((const v2f*)b2)[2];
        const v2f bb2_3 = ((const v2f*)b2)[3];
        const v2f bb3   = ((const v2f*)b3)[0];

        const int eRow = (bBase + g) * 100 + i * 10;  // first edge index of row
        const size_t adjOff = (size_t)B * 200;

#pragma unroll
        for (int cc = 0; cc < 5; ++cc) {
            const int c = half * 5 + cc;
            const int j = (c == 0) ? i : (((c - 1) < i) ? (c - 1) : c);
            const v4f* src = (const v4f*)&sgb[(g * 10 + j) * GB_STRIDE];

            v2f a0 = bb2_0, a1 = bb2_1, a2 = bb2_2, a3 = bb2_3;
#pragma unroll
            for (int q = 0; q < 8; ++q) {
                const v4f s = ga[q] + src[q];
                const v4f h = __builtin_elementwise_max(s, s * NEG);
                const int k0 = 4 * q;
                a0 += h.x * w2p[4 * (k0 + 0) + 0];
                a1 += h.x * w2p[4 * (k0 + 0) + 1];
                a2 += h.x * w2p[4 * (k0 + 0) + 2];
                a3 += h.x * w2p[4 * (k0 + 0) + 3];
                a0 += h.y * w2p[4 * (k0 + 1) + 0];
                a1 += h.y * w2p[4 * (k0 + 1) + 1];
                a2 += h.y * w2p[4 * (k0 + 1) + 2];
                a3 += h.y * w2p[4 * (k0 + 1) + 3];
                a0 += h.z * w2p[4 * (k0 + 2) + 0];
                a1 += h.z * w2p[4 * (k0 + 2) + 1];
                a2 += h.z * w2p[4 * (k0 + 2) + 2];
                a3 += h.z * w2p[4 * (k0 + 2) + 3];
                a0 += h.w * w2p[4 * (k0 + 3) + 0];
                a1 += h.w * w2p[4 * (k0 + 3) + 1];
                a2 += h.w * w2p[4 * (k0 + 3) + 2];
                a3 += h.w * w2p[4 * (k0 + 3) + 3];
            }

            const v2f h20 = __builtin_elementwise_max(a0, a0 * NEG);
            const v2f h21 = __builtin_elementwise_max(a1, a1 * NEG);
            const v2f h22 = __builtin_elementwise_max(a2, a2 * NEG);
            const v2f h23 = __builtin_elementwise_max(a3, a3 * NEG);

            v2f ev = bb3;
            ev += h20.x * w3p[0];
            ev += h20.y * w3p[1];
            ev += h21.x * w3p[2];
            ev += h21.y * w3p[3];
            ev += h22.x * w3p[4];
            ev += h22.y * w3p[5];
            ev += h23.x * w3p[6];
            ev += h23.y * w3p[7];

            const int E = eRow + c;
            ((v2f*)out)[E] = ev;                         // 8B store
            out[adjOff + E] = (ev.y > ev.x) ? 1.0f : 0.0f;
        }
    }
}

extern "C" void kernel_launch(void* const* d_in, const int* in_sizes, int n_in,
                              void* d_out, int out_size, void* d_ws, size_t ws_size,
                              hipStream_t stream) {
    const float* pos = (const float*)d_in[0];
    const float* ori = (const float*)d_in[1];
    const float* Wp  = (const float*)d_in[2];
    const float* bp  = (const float*)d_in[3];
    const float* W1  = (const float*)d_in[4];
    const float* b1  = (const float*)d_in[5];
    const float* W2  = (const float*)d_in[6];
    const float* b2  = (const float*)d_in[7];
    const float* W3  = (const float*)d_in[8];
    const float* b3  = (const float*)d_in[9];
    float* out = (float*)d_out;

    const int B = in_sizes[0] / 20;           // 16384
    const int nBlocks = (B + G - 1) / G;      // 1366

    gpn_kernel<<<nBlocks, 256, 0, stream>>>(pos, ori, Wp, bp, W1, b1, W2, b2,
                                            W3, b3, out, B);
}

// Round 5
// 95.170 us; speedup vs baseline: 1.1859x; 1.0876x over previous
//
#include <hip/hip_runtime.h>

// GraphProposalNetwork on MI355X — round 5.
// Algebra: feat=x@Wp+bp is linear into W1 and pair=[vi,vj], so
//   h1[b,i,j,:] = lrelu(g_a[b,i,:] + g_b[b,j,:]) with per-node g = x@(Wp@W1half)+bias.
// Round-5: (a) tiny pre-kernel fuses M=Wp@[W1a|W1b] (3x64) + bias c into d_ws;
// main kernel reads M/c via wave-uniform s_load (phase A + one barrier deleted).
// (b) K-sliced layer 2: per q, the 4 W2 rows (32 floats) are SGPR-resident and
// amortized across 5 independent edge streams -> no per-edge W2 reload, 5-way ILP.

typedef float v2f __attribute__((ext_vector_type(2)));
typedef float v4f __attribute__((ext_vector_type(4)));

constexpr int G = 12;            // graphs per block (240 of 256 lanes active)
constexpr int GB_STRIDE = 36;    // floats per gb row: 32 + 4 pad (16B aligned)
constexpr float NEG = 0.2f;

// ---- pre-kernel: M = Wp@[W1a|W1b] (3x64) at ws[0..191], c at ws[192..255] ----
__global__ __launch_bounds__(256, 1) void fuse_kernel(
    const float* __restrict__ Wp, const float* __restrict__ bp,
    const float* __restrict__ W1, const float* __restrict__ b1,
    float* __restrict__ ws)
{
    const int t = threadIdx.x;
    if (t < 192) {
        const int d = t >> 6, k = t & 63;
        const int kk = k & 31;
        const int fo = (k < 32) ? 0 : 16;
        float acc = 0.f;
#pragma unroll
        for (int f = 0; f < 16; ++f)
            acc = fmaf(Wp[d * 16 + f], W1[(fo + f) * 32 + kk], acc);
        ws[d * 64 + k] = acc;
    } else {
        const int k = t - 192;
        const int kk = k & 31;
        const int fo = (k < 32) ? 0 : 16;
        float acc = 0.f;
#pragma unroll
        for (int f = 0; f < 16; ++f)
            acc = fmaf(bp[f], W1[(fo + f) * 32 + kk], acc);
        if (k < 32) acc += b1[k];
        ws[192 + k] = acc;
    }
}

__global__ __launch_bounds__(256, 4) void gpn_kernel(
    const float* __restrict__ pos,  // (B,10,2)
    const float* __restrict__ ori,  // (B,10,1)
    const float* __restrict__ ws,   // fused M (192) ++ c (64)
    const float* __restrict__ W2,   // (32,8)
    const float* __restrict__ b2,   // (8)
    const float* __restrict__ W3,   // (8,2)
    const float* __restrict__ b3,   // (2)
    float* __restrict__ out,        // big_edge (B*100*2) ++ adjacency (B*100)
    int B)
{
    __shared__ float sgb[G * 10 * GB_STRIDE]; // per-node g_b halves (17.3 KB)

    const int t = threadIdx.x;
    const int bBase = blockIdx.x * G;
    const int remG = B - bBase;
    const int nLanes = ((remG < G) ? remG : G) * 10 * 2;

    // ---- Phase B: per-node projection. Two lanes share row r = t>>1; both
    // compute the register a-half; each writes 4 of 8 b-half float4s to LDS.
    // M/c indices are wave-uniform constants -> s_load from ws. ----
    const v4f* m4 = (const v4f*)ws;          // 48 v4f (3 rows x 16)
    const v4f* c4 = (const v4f*)(ws + 192);  // 16 v4f

    v4f ga[8];
    const int r = t >> 1;
    const int half = t & 1;
    const int g = r / 10;
    const int i = r - g * 10;
    if (t < nLanes) {
        const int node = bBase * 10 + r;
        const v2f p = ((const v2f*)pos)[node];
        const float o = ori[node];
        v4f* dst = (v4f*)&sgb[r * GB_STRIDE];
#pragma unroll
        for (int q = 0; q < 8; ++q) {
            v4f gg = c4[q];
            gg += p.x * m4[q];
            gg += p.y * m4[16 + q];
            gg += o   * m4[32 + q];
            ga[q] = gg;
        }
#pragma unroll
        for (int qq = 0; qq < 4; ++qq) {
            const int q = 8 + half * 4 + qq;
            v4f gg = c4[q];
            gg += p.x * m4[q];
            gg += p.y * m4[16 + q];
            gg += o   * m4[32 + q];
            dst[q - 8] = gg;
        }
    }
    __syncthreads();

    // ---- Phase C: 5 edges per lane, K-sliced layer 2. Per q the 4 W2 rows
    // stay SGPR-resident and feed all 5 edge streams (5-way ILP). ----
    if (t < nLanes) {
        const v2f* w2p = (const v2f*)W2;  // row k: pairs [4k..4k+3]
        const v2f* w3p = (const v2f*)W3;
        const v2f bb2_0 = ((const v2f*)b2)[0];
        const v2f bb2_1 = ((const v2f*)b2)[1];
        const v2f bb2_2 = ((const v2f*)b2)[2];
        const v2f bb2_3 = ((const v2f*)b2)[3];
        const v2f bb3   = ((const v2f*)b3)[0];

        // LDS source rows for this lane's 5 edges
        const v4f* src[5];
#pragma unroll
        for (int e = 0; e < 5; ++e) {
            const int c = half * 5 + e;
            const int j = (c == 0) ? i : (((c - 1) < i) ? (c - 1) : c);
            src[e] = (const v4f*)&sgb[(g * 10 + j) * GB_STRIDE];
        }

        v2f A[5][4];
#pragma unroll
        for (int e = 0; e < 5; ++e) {
            A[e][0] = bb2_0; A[e][1] = bb2_1; A[e][2] = bb2_2; A[e][3] = bb2_3;
        }

#pragma unroll
        for (int q = 0; q < 8; ++q) {
            const v4f gaq = ga[q];
            const int k0 = 4 * q;
            // 8 W2 pairs for this k-slice (wave-uniform -> SGPRs, loaded once per q)
            const v2f w00 = w2p[4 * (k0 + 0) + 0], w01 = w2p[4 * (k0 + 0) + 1],
                      w02 = w2p[4 * (k0 + 0) + 2], w03 = w2p[4 * (k0 + 0) + 3];
            const v2f w10 = w2p[4 * (k0 + 1) + 0], w11 = w2p[4 * (k0 + 1) + 1],
                      w12 = w2p[4 * (k0 + 1) + 2], w13 = w2p[4 * (k0 + 1) + 3];
            const v2f w20 = w2p[4 * (k0 + 2) + 0], w21 = w2p[4 * (k0 + 2) + 1],
                      w22 = w2p[4 * (k0 + 2) + 2], w23 = w2p[4 * (k0 + 2) + 3];
            const v2f w30 = w2p[4 * (k0 + 3) + 0], w31 = w2p[4 * (k0 + 3) + 1],
                      w32 = w2p[4 * (k0 + 3) + 2], w33 = w2p[4 * (k0 + 3) + 3];
#pragma unroll
            for (int e = 0; e < 5; ++e) {
                const v4f s = gaq + src[e][q];
                const v4f h = __builtin_elementwise_max(s, s * NEG);
                A[e][0] += h.x * w00; A[e][1] += h.x * w01;
                A[e][2] += h.x * w02; A[e][3] += h.x * w03;
                A[e][0] += h.y * w10; A[e][1] += h.y * w11;
                A[e][2] += h.y * w12; A[e][3] += h.y * w13;
                A[e][0] += h.z * w20; A[e][1] += h.z * w21;
                A[e][2] += h.z * w22; A[e][3] += h.z * w23;
                A[e][0] += h.w * w30; A[e][1] += h.w * w31;
                A[e][2] += h.w * w32; A[e][3] += h.w * w33;
            }
        }

        // ---- layer 3 + stores (immediate, no buffering) ----
        const int eRow = (bBase + g) * 100 + i * 10;
        const size_t adjOff = (size_t)B * 200;
#pragma unroll
        for (int e = 0; e < 5; ++e) {
            const v2f h20 = __builtin_elementwise_max(A[e][0], A[e][0] * NEG);
            const v2f h21 = __builtin_elementwise_max(A[e][1], A[e][1] * NEG);
            const v2f h22 = __builtin_elementwise_max(A[e][2], A[e][2] * NEG);
            const v2f h23 = __builtin_elementwise_max(A[e][3], A[e][3] * NEG);

            v2f ev = bb3;
            ev += h20.x * w3p[0];
            ev += h20.y * w3p[1];
            ev += h21.x * w3p[2];
            ev += h21.y * w3p[3];
            ev += h22.x * w3p[4];
            ev += h22.y * w3p[5];
            ev += h23.x * w3p[6];
            ev += h23.y * w3p[7];

            const int E = eRow + half * 5 + e;
            ((v2f*)out)[E] = ev;
            out[adjOff + E] = (ev.y > ev.x) ? 1.0f : 0.0f;
        }
    }
}

extern "C" void kernel_launch(void* const* d_in, const int* in_sizes, int n_in,
                              void* d_out, int out_size, void* d_ws, size_t ws_size,
                              hipStream_t stream) {
    const float* pos = (const float*)d_in[0];
    const float* ori = (const float*)d_in[1];
    const float* Wp  = (const float*)d_in[2];
    const float* bp  = (const float*)d_in[3];
    const float* W1  = (const float*)d_in[4];
    const float* b1  = (const float*)d_in[5];
    const float* W2  = (const float*)d_in[6];
    const float* b2  = (const float*)d_in[7];
    const float* W3  = (const float*)d_in[8];
    const float* b3  = (const float*)d_in[9];
    float* out = (float*)d_out;
    float* ws  = (float*)d_ws;

    const int B = in_sizes[0] / 20;           // 16384
    const int nBlocks = (B + G - 1) / G;      // 1366

    fuse_kernel<<<1, 256, 0, stream>>>(Wp, bp, W1, b1, ws);
    gpn_kernel<<<nBlocks, 256, 0, stream>>>(pos, ori, ws, W2, b2, W3, b3, out, B);
}

// Round 6
// 94.858 us; speedup vs baseline: 1.1898x; 1.0033x over previous
//
#include <hip/hip_runtime.h>

// GraphProposalNetwork on MI355X — round 6.
// Algebra: feat=x@Wp+bp is linear into W1 and pair=[vi,vj], so
//   h1[b,i,j,:] = lrelu(g_a[b,i,:] + g_b[b,j,:]) with per-node g = x@(Wp@W1half)+bias.
// Round-6: 1 lane per (graph,i) row, all 10 edges; K-sliced layer 2 so each
// W2 slice (16 dwords, SGPR) feeds 10 independent accumulator streams (10-way
// ILP to hide FMA + s_load latency). 128-thread blocks, launch_bounds(128,3)
// -> 170-VGPR cap, ~5.3 blocks/CU all co-resident. Batched epilogue stores.

typedef float v2f __attribute__((ext_vector_type(2)));
typedef float v4f __attribute__((ext_vector_type(4)));

constexpr int G = 12;            // graphs per block (120 of 128 lanes active)
constexpr int GB_STRIDE = 36;    // floats per gb row: 32 + 4 pad (16B aligned)
constexpr float NEG = 0.2f;

// ---- pre-kernel: M = Wp@[W1a|W1b] (3x64) at ws[0..191], c at ws[192..255] ----
__global__ __launch_bounds__(256, 1) void fuse_kernel(
    const float* __restrict__ Wp, const float* __restrict__ bp,
    const float* __restrict__ W1, const float* __restrict__ b1,
    float* __restrict__ ws)
{
    const int t = threadIdx.x;
    if (t < 192) {
        const int d = t >> 6, k = t & 63;
        const int kk = k & 31;
        const int fo = (k < 32) ? 0 : 16;
        float acc = 0.f;
#pragma unroll
        for (int f = 0; f < 16; ++f)
            acc = fmaf(Wp[d * 16 + f], W1[(fo + f) * 32 + kk], acc);
        ws[d * 64 + k] = acc;
    } else {
        const int k = t - 192;
        const int kk = k & 31;
        const int fo = (k < 32) ? 0 : 16;
        float acc = 0.f;
#pragma unroll
        for (int f = 0; f < 16; ++f)
            acc = fmaf(bp[f], W1[(fo + f) * 32 + kk], acc);
        if (k < 32) acc += b1[k];
        ws[192 + k] = acc;
    }
}

__global__ __launch_bounds__(128, 3) void gpn_kernel(
    const float* __restrict__ pos,  // (B,10,2)
    const float* __restrict__ ori,  // (B,10,1)
    const float* __restrict__ ws,   // fused M (192) ++ c (64)
    const float* __restrict__ W2,   // (32,8)
    const float* __restrict__ b2,   // (8)
    const float* __restrict__ W3,   // (8,2)
    const float* __restrict__ b3,   // (2)
    float* __restrict__ out,        // big_edge (B*100*2) ++ adjacency (B*100)
    int B)
{
    __shared__ float sgb[G * 10 * GB_STRIDE]; // per-node g_b halves (17.3 KB)

    const int t = threadIdx.x;
    const int bBase = blockIdx.x * G;
    const int remG = B - bBase;
    const int nRows = ((remG < G) ? remG : G) * 10;

    const v4f* m4 = (const v4f*)ws;          // 48 v4f (3 rows x 16)
    const v4f* c4 = (const v4f*)(ws + 192);  // 16 v4f

    // ---- Phase B: lane owns row r=(g,i); a-half (k<32) in registers,
    // b-half (k>=32) to LDS. M/c reads are wave-uniform -> s_load. ----
    v4f ga[8];
    const int r = t;
    const int g = r / 10;
    const int i = r - g * 10;
    if (r < nRows) {
        const int node = bBase * 10 + r;
        const v2f p = ((const v2f*)pos)[node];
        const float o = ori[node];
        v4f* dst = (v4f*)&sgb[r * GB_STRIDE];
#pragma unroll
        for (int q = 0; q < 8; ++q) {
            v4f gg = c4[q];
            gg += p.x * m4[q];
            gg += p.y * m4[16 + q];
            gg += o   * m4[32 + q];
            ga[q] = gg;
        }
#pragma unroll
        for (int q = 8; q < 16; ++q) {
            v4f gg = c4[q];
            gg += p.x * m4[q];
            gg += p.y * m4[16 + q];
            gg += o   * m4[32 + q];
            dst[q - 8] = gg;
        }
    }
    __syncthreads();

    // ---- Phase C: 10 edges per lane, K-sliced layer 2. Per q the 4 W2 rows
    // (16 dwords) are SGPR-resident and feed 10 independent streams. ----
    if (r < nRows) {
        const v2f* w2p = (const v2f*)W2;  // row k: pairs [4k..4k+3]
        const v2f* w3p = (const v2f*)W3;
        const v2f bb2_0 = ((const v2f*)b2)[0];
        const v2f bb2_1 = ((const v2f*)b2)[1];
        const v2f bb2_2 = ((const v2f*)b2)[2];
        const v2f bb2_3 = ((const v2f*)b2)[3];
        const v2f bb3   = ((const v2f*)b3)[0];

        // LDS source rows for the 10 edges (c-order)
        const v4f* src[10];
#pragma unroll
        for (int c = 0; c < 10; ++c) {
            const int j = (c == 0) ? i : (((c - 1) < i) ? (c - 1) : c);
            src[c] = (const v4f*)&sgb[(g * 10 + j) * GB_STRIDE];
        }

        v2f A[10][4];
#pragma unroll
        for (int e = 0; e < 10; ++e) {
            A[e][0] = bb2_0; A[e][1] = bb2_1; A[e][2] = bb2_2; A[e][3] = bb2_3;
        }

#pragma unroll
        for (int q = 0; q < 8; ++q) {
            const v4f gaq = ga[q];
            const int k0 = 4 * q;
            const v2f w00 = w2p[4 * (k0 + 0) + 0], w01 = w2p[4 * (k0 + 0) + 1],
                      w02 = w2p[4 * (k0 + 0) + 2], w03 = w2p[4 * (k0 + 0) + 3];
            const v2f w10 = w2p[4 * (k0 + 1) + 0], w11 = w2p[4 * (k0 + 1) + 1],
                      w12 = w2p[4 * (k0 + 1) + 2], w13 = w2p[4 * (k0 + 1) + 3];
            const v2f w20 = w2p[4 * (k0 + 2) + 0], w21 = w2p[4 * (k0 + 2) + 1],
                      w22 = w2p[4 * (k0 + 2) + 2], w23 = w2p[4 * (k0 + 2) + 3];
            const v2f w30 = w2p[4 * (k0 + 3) + 0], w31 = w2p[4 * (k0 + 3) + 1],
                      w32 = w2p[4 * (k0 + 3) + 2], w33 = w2p[4 * (k0 + 3) + 3];
#pragma unroll
            for (int e = 0; e < 10; ++e) {
                const v4f s = gaq + src[e][q];
                const v4f h = __builtin_elementwise_max(s, s * NEG);
                A[e][0] += h.x * w00; A[e][1] += h.x * w01;
                A[e][2] += h.x * w02; A[e][3] += h.x * w03;
                A[e][0] += h.y * w10; A[e][1] += h.y * w11;
                A[e][2] += h.y * w12; A[e][3] += h.y * w13;
                A[e][0] += h.z * w20; A[e][1] += h.z * w21;
                A[e][2] += h.z * w22; A[e][3] += h.z * w23;
                A[e][0] += h.w * w30; A[e][1] += h.w * w31;
                A[e][2] += h.w * w32; A[e][3] += h.w * w33;
            }
        }

        // ---- layer 3 into register buffers (compile-time indexed) ----
        float evb[20];
        float adjv[10];
#pragma unroll
        for (int e = 0; e < 10; ++e) {
            const v2f h20 = __builtin_elementwise_max(A[e][0], A[e][0] * NEG);
            const v2f h21 = __builtin_elementwise_max(A[e][1], A[e][1] * NEG);
            const v2f h22 = __builtin_elementwise_max(A[e][2], A[e][2] * NEG);
            const v2f h23 = __builtin_elementwise_max(A[e][3], A[e][3] * NEG);

            v2f ev = bb3;
            ev += h20.x * w3p[0];
            ev += h20.y * w3p[1];
            ev += h21.x * w3p[2];
            ev += h21.y * w3p[3];
            ev += h22.x * w3p[4];
            ev += h22.y * w3p[5];
            ev += h23.x * w3p[6];
            ev += h23.y * w3p[7];

            evb[2 * e]     = ev.x;
            evb[2 * e + 1] = ev.y;
            adjv[e] = (ev.y > ev.x) ? 1.0f : 0.0f;
        }

        // ---- batched stores: 5x dwordx4 big_edge + 5x dwordx2 adjacency ----
        const int eRow = (bBase + g) * 100 + i * 10;     // first edge of row
        v4f* bo = (v4f*)(out + (size_t)eRow * 2);        // 80B-aligned
#pragma unroll
        for (int q = 0; q < 5; ++q) {
            v4f vv = {evb[4 * q], evb[4 * q + 1], evb[4 * q + 2], evb[4 * q + 3]};
            bo[q] = vv;
        }
        v2f* ao = (v2f*)(out + (size_t)B * 200 + eRow);  // 8B-aligned
#pragma unroll
        for (int q = 0; q < 5; ++q) {
            v2f vv = {adjv[2 * q], adjv[2 * q + 1]};
            ao[q] = vv;
        }
    }
}

extern "C" void kernel_launch(void* const* d_in, const int* in_sizes, int n_in,
                              void* d_out, int out_size, void* d_ws, size_t ws_size,
                              hipStream_t stream) {
    const float* pos = (const float*)d_in[0];
    const float* ori = (const float*)d_in[1];
    const float* Wp  = (const float*)d_in[2];
    const float* bp  = (const float*)d_in[3];
    const float* W1  = (const float*)d_in[4];
    const float* b1  = (const float*)d_in[5];
    const float* W2  = (const float*)d_in[6];
    const float* b2  = (const float*)d_in[7];
    const float* W3  = (const float*)d_in[8];
    const float* b3  = (const float*)d_in[9];
    float* out = (float*)d_out;
    float* ws  = (float*)d_ws;

    const int B = in_sizes[0] / 20;           // 16384
    const int nBlocks = (B + G - 1) / G;      // 1366

    fuse_kernel<<<1, 256, 0, stream>>>(Wp, bp, W1, b1, ws);
    gpn_kernel<<<nBlocks, 128, 0, stream>>>(pos, ori, ws, W2, b2, W3, b3, out, B);
}